// Round 11
// baseline (61.260 us; speedup 1.0000x reference)
//
#include <hip/hip_runtime.h>

typedef __bf16 bf16x8 __attribute__((ext_vector_type(8)));
typedef __bf16 bf16x4 __attribute__((ext_vector_type(4)));
typedef float f32x4 __attribute__((ext_vector_type(4)));
typedef unsigned short u16x8 __attribute__((ext_vector_type(8)));

union FragU { u16x8 u; bf16x8 b; };
union PackU { bf16x4 v; unsigned long long q; };

__device__ __forceinline__ unsigned short bfbits(float f) {
  __bf16 h = (__bf16)f;
  union { __bf16 h; unsigned short s; } cv; cv.h = h;
  return cv.s;
}

#define MFMA16(a, b, c) __builtin_amdgcn_mfma_f32_16x16x32_bf16((a), (b), (c), 0, 0, 0)

// 0.125 (1/sqrt(64)) * log2(e): softmax done in base-2
#define QSCALE 0.18033688011112042f

// ---------------- W -> fragment-order bf16: WF[m][c][t][lane][8] ----------------
__global__ __launch_bounds__(256) void wt_kernel(
    const float* __restrict__ Wq, const float* __restrict__ Wk, const float* __restrict__ Wv,
    unsigned short* __restrict__ WF)
{
  const int m = blockIdx.x >> 5;         // 0..2
  const int c = blockIdx.x & 31;         // 0..31
  const float* W = (m == 0) ? Wq : ((m == 1) ? Wk : Wv);
  const int t = threadIdx.x >> 6;
  const int lane = threadIdx.x & 63;
  const int l15 = lane & 15;
  const int g = lane >> 4;
  unsigned short* dst = WF + ((((size_t)m * 32 + c) * 4 + t) * 64 + lane) * 8;
#pragma unroll
  for (int e = 0; e < 8; ++e)
    dst[e] = bfbits(W[(size_t)(32 * c + 8 * g + e) * 64 + (16 * t + l15)]);
}

// ---------------- fused QKV projection: async-DMA x ring, barrier-free ----------------
// grid 512 x 128 thr (2 waves x 16 rows). Per wave: x streamed via
// global_load_lds (16B) into a private 4-slot LDS ring (8KB chunks = 4 c-iters),
// 3 chunks in flight (24 x 1KB DMA outstanding; no VGPR cost, no barriers).
// Completion gated by counted s_waitcnt vmcnt(16): >=64 VMEM ops are issued
// after any chunk before its wait, so "all but newest 16 done" => chunk landed.
// Global source pre-swizzled (u ^= row&7) so stride-512B ds_read_b128 is
// conflict-free. W = R5-proven reg double-buffer from fragment-ordered WF.
__global__ __launch_bounds__(128, 1) void proj_kernel(
    const float* __restrict__ x, const unsigned short* __restrict__ WF,
    const float* __restrict__ bq, const float* __restrict__ bk, const float* __restrict__ bv,
    unsigned short* __restrict__ Qb, unsigned short* __restrict__ KF,
    unsigned short* __restrict__ VF)
{
  __shared__ __align__(16) float ldsx[2][4][2048];   // 64 KB: [wave][ring][16r x 128f]
  const int tid = threadIdx.x;
  const int lane = tid & 63;
  const int wid = tid >> 6;               // 0..1
  const int l15 = lane & 15;
  const int g = lane >> 4;
  const int h = lane >> 5;                // row within pair for staging
  const int u = lane & 31;                // 16B unit within 512B row-chunk
  const int row0 = blockIdx.x * 32 + wid * 16;

  f32x4 accQ[4], accK[4], accV[4];
  const f32x4 zero = {0.f, 0.f, 0.f, 0.f};
#pragma unroll
  for (int i = 0; i < 4; ++i) { accQ[i] = zero; accK[i] = zero; accV[i] = zero; }

  const float* xw = x + (size_t)row0 * 1024;
  bf16x8 wq[2][4], wk[2][4], wv[2][4];

  // async DMA one 8KB chunk (4 c-iters of 16 rows): 8 instrs x 1KB.
  // instr j covers rows 2j,2j+1; LDS dest linear (lane*16); global src swizzled.
#define XDMA(CK) { _Pragma("unroll") for (int j = 0; j < 8; ++j) { \
    const int r_ = 2 * j + h; \
    const float* gs_ = xw + (size_t)r_ * 1024 + (CK) * 128 + ((u ^ (r_ & 7)) * 4); \
    __builtin_amdgcn_global_load_lds( \
        (const __attribute__((address_space(1))) void*)gs_, \
        (__attribute__((address_space(3))) void*)&ldsx[wid][(CK) & 3][j * 256], \
        16, 0, 0); } }

#define PLDW(WS, C) { _Pragma("unroll") for (int t = 0; t < 4; ++t) { \
    wq[WS][t] = *(const bf16x8*)(WF + ((((size_t)0 * 32 + (C)) * 4 + t) * 64 + lane) * 8); \
    wk[WS][t] = *(const bf16x8*)(WF + ((((size_t)1 * 32 + (C)) * 4 + t) * 64 + lane) * 8); \
    wv[WS][t] = *(const bf16x8*)(WF + ((((size_t)2 * 32 + (C)) * 4 + t) * 64 + lane) * 8); } }

  // one c-iter: swizzled ds_read_b128 x2, cvt, 12 MFMA, W-refill
#define PHALF2(SLOT, CL, WS, CWN) { \
    const int ku_ = l15 & 7; \
    const float* xb_ = &ldsx[wid][SLOT][(size_t)l15 * 128]; \
    const f32x4 x0_ = *(const f32x4*)(xb_ + ((((CL) * 8 + 2 * g) ^ ku_) * 4)); \
    const f32x4 x1_ = *(const f32x4*)(xb_ + ((((CL) * 8 + 2 * g + 1) ^ ku_) * 4)); \
    FragU xf; \
    _Pragma("unroll") for (int i_ = 0; i_ < 4; ++i_) { \
      xf.b[i_] = (__bf16)x0_[i_]; xf.b[4 + i_] = (__bf16)x1_[i_]; } \
    _Pragma("unroll") for (int t = 0; t < 4; ++t) { \
      accQ[t] = MFMA16(xf.b, wq[WS][t], accQ[t]); \
      accK[t] = MFMA16(xf.b, wk[WS][t], accK[t]); \
      accV[t] = MFMA16(wv[WS][t], xf.b, accV[t]); } \
    if ((CWN) < 32) PLDW(WS, CWN); }

  // prologue: 3 chunks in flight, W for c=0,1
  XDMA(0) XDMA(1) XDMA(2)
  PLDW(0, 0) PLDW(1, 1)

#pragma unroll 1
  for (int w0 = 0; w0 < 8; ++w0) {
    // all but the newest 16 VMEM ops complete => chunk w0 is in LDS
    asm volatile("s_waitcnt vmcnt(16)" ::: "memory");
    __builtin_amdgcn_sched_barrier(0);
    if (w0 < 5) XDMA(w0 + 3)            // refill ring slot (w0+3)&3 != w0&3
    const int c = w0 * 4;
    const int sl = w0 & 3;
    PHALF2(sl, 0, 0, c + 2)
    PHALF2(sl, 1, 1, c + 3)
    PHALF2(sl, 2, 0, c + 4)
    PHALF2(sl, 3, 1, c + 5)
  }

  const int b = row0 >> 12;
  const int q0 = row0 & 4095;
  const int kt = q0 >> 6;
  const int r16 = (q0 >> 4) & 3;
  unsigned short* Qbase = Qb + (size_t)b * 4096 * 64;
#pragma unroll
  for (int t = 0; t < 4; ++t) {
    const int hh = 16 * t + l15;
    const float bqv = bq[hh];
#pragma unroll
    for (int r = 0; r < 4; ++r)
      Qbase[(size_t)(q0 + 4 * g + r) * 64 + hh] = bfbits((accQ[t][r] + bqv) * QSCALE);
  }
  unsigned short* KFb = KF + ((size_t)b * 64 + kt) * 4096;
  unsigned short* VFb = VF + ((size_t)b * 64 + kt) * 4096;
#pragma unroll
  for (int t = 0; t < 4; ++t) {
    const int hh = 16 * t + l15;
    const float bkv = bk[hh];
#pragma unroll
    for (int r = 0; r < 4; ++r) {
      KFb[(size_t)((r16 * 2 + (t >> 1)) * 64 + (t & 1) * 32 + (l15 >> 3) * 16 + 4 * g + r) * 8 +
          (l15 & 7)] = bfbits(accK[t][r] + bkv);
      const int hv = 16 * t + 4 * g + r;
      VFb[(size_t)((t * 2 + (r16 >> 1)) * 64 + (r16 & 1) * 32 + (l15 >> 3) * 16 + 4 * g + r) * 8 +
          (l15 & 7)] = bfbits(accV[t][r] + bv[hv]);
    }
  }
}

// ---------------- flash attention: 32 q-rows/wave, k-split 4 (R5-proven) ----------------
__global__ __launch_bounds__(256, 2) void flash_kernel(
    const unsigned short* __restrict__ Qb, const unsigned short* __restrict__ KF,
    const unsigned short* __restrict__ VF, float* __restrict__ out)
{
  __shared__ __align__(16) unsigned char lds[36864];
  const int tid = threadIdx.x;
  const int lane = tid & 63;
  const int w = tid >> 6;                 // 0..3 = k-split
  const int l15 = lane & 15;
  const int g = lane >> 4;
  const int bid = blockIdx.x;
  const int xcd = bid & 7;
  const int b = xcd >> 1;
  const int qt = (bid >> 3) * 2 + (xcd & 1);   // 0..127
  const int q0 = qt * 32;

  const unsigned short* Qp = Qb + (size_t)b * 4096 * 64;
  const unsigned short* KFb = KF + (size_t)b * 262144;
  const unsigned short* VFb = VF + (size_t)b * 262144;

  const bf16x8 qfA0 = *(const bf16x8*)(Qp + (size_t)(q0 + l15) * 64 + 8 * g);
  const bf16x8 qfA1 = *(const bf16x8*)(Qp + (size_t)(q0 + l15) * 64 + 32 + 8 * g);
  const bf16x8 qfB0 = *(const bf16x8*)(Qp + (size_t)(q0 + 16 + l15) * 64 + 8 * g);
  const bf16x8 qfB1 = *(const bf16x8*)(Qp + (size_t)(q0 + 16 + l15) * 64 + 32 + 8 * g);

  f32x4 O_A[4], O_B[4];
  const f32x4 zero = {0.f, 0.f, 0.f, 0.f};
#pragma unroll
  for (int i = 0; i < 4; ++i) { O_A[i] = zero; O_B[i] = zero; }
  float mA = -INFINITY, lA = 0.f, mB = -INFINITY, lB = 0.f;
  unsigned short* PwA = (unsigned short*)lds + (w * 2 + 0) * 1152;
  unsigned short* PwB = (unsigned short*)lds + (w * 2 + 1) * 1152;

#define SM_HALF(S, mvar, lvar, OA, PW) { \
  float mt = fmaxf(fmaxf(S[0][0], S[0][1]), fmaxf(S[0][2], S[0][3])); \
  _Pragma("unroll") for (int t = 1; t < 4; ++t) \
    _Pragma("unroll") for (int r = 0; r < 4; ++r) mt = fmaxf(mt, S[t][r]); \
  mt = fmaxf(mt, __shfl_xor(mt, 16)); \
  mt = fmaxf(mt, __shfl_xor(mt, 32)); \
  if (!__all(mt <= mvar + 8.0f)) { \
    const float mnew = fmaxf(mvar, mt); \
    const float alpha = __builtin_amdgcn_exp2f(mvar - mnew); \
    mvar = mnew; lvar *= alpha; \
    _Pragma("unroll") for (int r = 0; r < 4; ++r) { \
      const float ar = __shfl(alpha, 4 * g + r); \
      OA[0][r] *= ar; OA[1][r] *= ar; OA[2][r] *= ar; OA[3][r] *= ar; } \
  } \
  float ps = 0.f; \
  _Pragma("unroll") for (int t = 0; t < 4; ++t) { \
    const float p0 = __builtin_amdgcn_exp2f(S[t][0] - mvar); \
    const float p1 = __builtin_amdgcn_exp2f(S[t][1] - mvar); \
    const float p2 = __builtin_amdgcn_exp2f(S[t][2] - mvar); \
    const float p3 = __builtin_amdgcn_exp2f(S[t][3] - mvar); \
    ps += (p0 + p1) + (p2 + p3); \
    PackU pk_; pk_.v[0] = (__bf16)p0; pk_.v[1] = (__bf16)p1; \
    pk_.v[2] = (__bf16)p2; pk_.v[3] = (__bf16)p3; \
    *(unsigned long long*)((PW) + l15 * 72 + 16 * t + 4 * g) = pk_.q; } \
  ps += __shfl_xor(ps, 16); \
  ps += __shfl_xor(ps, 32); \
  lvar += ps; }

#pragma unroll 1
  for (int kt = w; kt < 64; kt += 4) {
    const unsigned short* Kt = KFb + kt * 4096;
    const unsigned short* Vt = VFb + kt * 4096;
    bf16x8 kf[8], vf[8];
#pragma unroll
    for (int j = 0; j < 8; ++j) kf[j] = *(const bf16x8*)(Kt + (j * 64 + lane) * 8);
#pragma unroll
    for (int j = 0; j < 8; ++j) vf[j] = *(const bf16x8*)(Vt + (j * 64 + lane) * 8);
    f32x4 S_A[4], S_B[4];
#pragma unroll
    for (int t = 0; t < 4; ++t) {
      S_A[t] = zero;
      S_A[t] = MFMA16(kf[2 * t], qfA0, S_A[t]);
      S_A[t] = MFMA16(kf[2 * t + 1], qfA1, S_A[t]);
      S_B[t] = zero;
      S_B[t] = MFMA16(kf[2 * t], qfB0, S_B[t]);
      S_B[t] = MFMA16(kf[2 * t + 1], qfB1, S_B[t]);
    }
    SM_HALF(S_A, mA, lA, O_A, PwA)
    SM_HALF(S_B, mB, lB, O_B, PwB)
#pragma unroll
    for (int s = 0; s < 2; ++s) {
      const bf16x8 paA = *(const bf16x8*)(PwA + l15 * 72 + 32 * s + 8 * g);
      const bf16x8 paB = *(const bf16x8*)(PwB + l15 * 72 + 32 * s + 8 * g);
#pragma unroll
      for (int nt = 0; nt < 4; ++nt) {
        O_A[nt] = MFMA16(paA, vf[2 * nt + s], O_A[nt]);
        O_B[nt] = MFMA16(paB, vf[2 * nt + s], O_B[nt]);
      }
    }
  }

  // ---- in-LDS combine of the 4 k-split partials ----
  __syncthreads();
  float* O_l = (float*)lds;                 // [8][16][68]
  float* mlp = (float*)(lds + 34816);       // [8][16][2]
#pragma unroll
  for (int nt = 0; nt < 4; ++nt)
#pragma unroll
    for (int r = 0; r < 4; ++r) {
      O_l[((w * 2 + 0) * 16 + 4 * g + r) * 68 + 16 * nt + l15] = O_A[nt][r];
      O_l[((w * 2 + 1) * 16 + 4 * g + r) * 68 + 16 * nt + l15] = O_B[nt][r];
    }
  if (g == 0) {
    mlp[((w * 2 + 0) * 16 + l15) * 2] = mA; mlp[((w * 2 + 0) * 16 + l15) * 2 + 1] = lA;
    mlp[((w * 2 + 1) * 16 + l15) * 2] = mB; mlp[((w * 2 + 1) * 16 + l15) * 2 + 1] = lB;
  }
  __syncthreads();

  const int q = tid >> 3;           // 0..31
  const int h0 = (tid & 7) * 8;     // 0..56
  const int qh = q >> 4, qr = q & 15;
  float M = -INFINITY;
#pragma unroll
  for (int s = 0; s < 4; ++s) M = fmaxf(M, mlp[((s * 2 + qh) * 16 + qr) * 2]);
  float L = 0.f;
  f32x4 a0 = zero, a1 = zero;
#pragma unroll
  for (int s = 0; s < 4; ++s) {
    const int rowi = (s * 2 + qh) * 16 + qr;
    const float wgt = __builtin_amdgcn_exp2f(mlp[rowi * 2] - M);
    L += wgt * mlp[rowi * 2 + 1];
    const f32x4 o0 = *(const f32x4*)&O_l[rowi * 68 + h0];
    const f32x4 o1 = *(const f32x4*)&O_l[rowi * 68 + h0 + 4];
#pragma unroll
    for (int i = 0; i < 4; ++i) { a0[i] += wgt * o0[i]; a1[i] += wgt * o1[i]; }
  }
  const float inv = 1.0f / L;
  float* ob = out + ((size_t)b * 4096 + qt * 32 + q) * 64 + h0;
  f32x4 r0 = {a0[0] * inv, a0[1] * inv, a0[2] * inv, a0[3] * inv};
  f32x4 r1 = {a1[0] * inv, a1[1] * inv, a1[2] * inv, a1[3] * inv};
  *(f32x4*)ob = r0;
  *(f32x4*)(ob + 4) = r1;
}

extern "C" void kernel_launch(void* const* d_in, const int* in_sizes, int n_in,
                              void* d_out, int out_size, void* d_ws, size_t ws_size,
                              hipStream_t stream) {
  const float* x  = (const float*)d_in[0];
  const float* Wq = (const float*)d_in[1];
  const float* bq = (const float*)d_in[2];
  const float* Wk = (const float*)d_in[3];
  const float* bk = (const float*)d_in[4];
  const float* Wv = (const float*)d_in[5];
  const float* bv = (const float*)d_in[6];

  char* ws = (char*)d_ws;
  unsigned short* WF = (unsigned short*)ws;                              // 384 KB
  unsigned short* Qb = (unsigned short*)(ws + (512u << 10));             // 2 MB
  unsigned short* KF = (unsigned short*)(ws + (512u << 10) + (2u << 20));// 2 MB
  unsigned short* VF = (unsigned short*)(ws + (512u << 10) + (4u << 20));// 2 MB
  float* out = (float*)d_out;

  hipLaunchKernelGGL(wt_kernel,    dim3(96),  dim3(256), 0, stream, Wq, Wk, Wv, WF);
  hipLaunchKernelGGL(proj_kernel,  dim3(512), dim3(128), 0, stream, x, WF, bq, bk, bv, Qb, KF, VF);
  hipLaunchKernelGGL(flash_kernel, dim3(512), dim3(256), 0, stream, Qb, KF, VF, out);
}